// Round 14
// baseline (302.693 us; speedup 1.0000x reference)
//
#include <hip/hip_runtime.h>
#include <hip/hip_bf16.h>
#include <math.h>

#define NN 50000
#define NE 800000
#define ETOT (NE + NN)
#define LEAKY 0.2f
#define BN_EPS 1e-5f

#define NB 256      // dst buckets
#define BSZ 196     // nodes per bucket (256*196 = 50176 >= NN)
#define NBB 128     // binning blocks
#define EPB ((ETOT + NBB - 1) / NBB)
#define PREPB 80    // prep blocks appended to binA grid

#define BN1 144   // 128 h1 cols + 4 es + 4 ed + 8 pad
#define BN2 48    // 40 h2 cols + es2 + ed2 + 6 pad

typedef unsigned short u16;
typedef unsigned int u32;
typedef short s16;
typedef __attribute__((ext_vector_type(8))) short bf16x8;
typedef __attribute__((ext_vector_type(4))) float f32x4;

__device__ __forceinline__ float bf2f(u32 u) {
    union { u32 i; float f; } x; x.i = u << 16; return x.f;
}
__device__ __forceinline__ float bf2f_lo(u32 u) {
    union { u32 i; float f; } x; x.i = u << 16; return x.f;
}
__device__ __forceinline__ float bf2f_hi(u32 u) {
    union { u32 i; float f; } x; x.i = u & 0xffff0000u; return x.f;
}
__device__ __forceinline__ u16 f2bf(float f) {
    __hip_bfloat16 b = __float2bfloat16(f);
    return *reinterpret_cast<u16*>(&b);
}

// ---- CSR build pass A fused with weight prep ----
__global__ __launch_bounds__(256) void k_binA_prep(
        const int* __restrict__ ei, int* __restrict__ cnt,
        const float* __restrict__ W1, const float* __restrict__ a1s,
        const float* __restrict__ a1d, const float* __restrict__ W2,
        const float* __restrict__ a2s, const float* __restrict__ a2d,
        u16* __restrict__ Wt1, u16* __restrict__ Wt2) {
    if (blockIdx.x < NBB) {
        __shared__ int hist[NB];
        int t = threadIdx.x;
        for (int i = t; i < NB; i += 256) hist[i] = 0;
        __syncthreads();
        int e0 = blockIdx.x * EPB, e1 = min(e0 + EPB, ETOT);
        for (int e = e0 + t; e < e1; e += 256) {
            int dst = (e < NE) ? ei[NE + e] : (e - NE);
            atomicAdd(&hist[dst / BSZ], 1);
        }
        __syncthreads();
        for (int b = t; b < NB; b += 256) cnt[b * NBB + blockIdx.x] = hist[b];
    } else {
        int tid = (blockIdx.x - NBB) * 256 + threadIdx.x;
        int nth = PREPB * 256;
        for (int idx = tid; idx < BN1 * 128; idx += nth) {
            int n = idx >> 7, k = idx & 127;
            float v = 0.f;
            if (n < 128) v = W1[k * 128 + n];
            else if (n < 132) {
                int h = n - 128; float s = 0.f;
                for (int c = 0; c < 32; ++c) s += W1[k * 128 + h * 32 + c] * a1s[h * 32 + c];
                v = s;
            } else if (n < 136) {
                int h = n - 132; float s = 0.f;
                for (int c = 0; c < 32; ++c) s += W1[k * 128 + h * 32 + c] * a1d[h * 32 + c];
                v = s;
            }
            Wt1[idx] = f2bf(v);
        }
        for (int idx = tid; idx < BN2 * 128; idx += nth) {
            int n = idx >> 7, k = idx & 127;
            float v = 0.f;
            if (n < 40) v = W2[k * 40 + n];
            else if (n == 40) { float s = 0.f; for (int c = 0; c < 40; ++c) s += W2[k * 40 + c] * a2s[c]; v = s; }
            else if (n == 41) { float s = 0.f; for (int c = 0; c < 40; ++c) s += W2[k * 40 + c] * a2d[c]; v = s; }
            Wt2[idx] = f2bf(v);
        }
    }
}

// single-kernel exclusive scan of exactly NB*NBB = 32768 ints
__global__ __launch_bounds__(1024) void k_scanONE(const int* __restrict__ in,
                                                  int* __restrict__ out) {
    __shared__ int sums[1024];
    int t = threadIdx.x;
    int4 loc[8];
    const int4* ip = (const int4*)(in + t * 32);
    int s = 0;
    #pragma unroll
    for (int i = 0; i < 8; ++i) {
        loc[i] = ip[i];
        s += loc[i].x + loc[i].y + loc[i].z + loc[i].w;
    }
    sums[t] = s;
    __syncthreads();
    for (int off = 1; off < 1024; off <<= 1) {
        int u = (t >= off) ? sums[t - off] : 0;
        __syncthreads();
        sums[t] += u;
        __syncthreads();
    }
    int run = (t == 0) ? 0 : sums[t - 1];
    int* op = out + t * 32;
    #pragma unroll
    for (int i = 0; i < 8; ++i) {
        op[i * 4 + 0] = run; run += loc[i].x;
        op[i * 4 + 1] = run; run += loc[i].y;
        op[i * 4 + 2] = run; run += loc[i].z;
        op[i * 4 + 3] = run; run += loc[i].w;
    }
}

__global__ __launch_bounds__(256) void k_binB(const int* __restrict__ ei,
                                              const int* __restrict__ excl,
                                              u32* __restrict__ packed) {
    __shared__ int cur[NB];
    int t = threadIdx.x;
    for (int b = t; b < NB; b += 256) cur[b] = excl[b * NBB + blockIdx.x];
    __syncthreads();
    int e0 = blockIdx.x * EPB, e1 = min(e0 + EPB, ETOT);
    for (int e = e0 + t; e < e1; e += 256) {
        int src, dst;
        if (e < NE) { src = ei[e]; dst = ei[NE + e]; }
        else        { src = e - NE; dst = e - NE; }
        int pos = atomicAdd(&cur[dst / BSZ], 1);
        packed[pos] = ((u32)src << 16) | (u32)dst;
    }
}

__global__ __launch_bounds__(256) void k_binC(const u32* __restrict__ packed,
                                              const int* __restrict__ excl,
                                              int* __restrict__ offsets,
                                              u16* __restrict__ ssrc) {
    __shared__ int hist[256];
    __shared__ int sc[256];
    __shared__ int cur[256];
    int b = blockIdx.x, t = threadIdx.x;
    int n0 = b * BSZ;
    int base = excl[b * NBB];
    int next = (b < NB - 1) ? excl[(b + 1) * NBB] : ETOT;
    int total = next - base;
    hist[t] = 0;
    __syncthreads();
    for (int i = t; i < total; i += 256) {
        int dst = (int)(packed[base + i] & 0xffffu);
        atomicAdd(&hist[dst - n0], 1);
    }
    __syncthreads();
    int v = hist[t];
    sc[t] = v;
    __syncthreads();
    #pragma unroll
    for (int off = 1; off < 256; off <<= 1) {
        int u = (t >= off) ? sc[t - off] : 0;
        __syncthreads();
        sc[t] += u;
        __syncthreads();
    }
    int exl = sc[t] - v;
    int node = n0 + t;
    if (t <= BSZ && node <= NN) {
        if (t < BSZ || node == NN) offsets[node] = base + exl;
    }
    cur[t] = exl;
    __syncthreads();
    for (int i = t; i < total; i += 256) {
        u32 pv = packed[base + i];
        int dst = (int)(pv & 0xffffu);
        int pos = atomicAdd(&cur[dst - n0], 1);
        ssrc[base + pos] = (u16)(pv >> 16);
    }
}

// MFMA GEMM layer 1: h1p[8][NN][16] bf16 panels + es1/ed1[NN,4] fp32.
__global__ __launch_bounds__(256) void k_mm1(const float* __restrict__ x,
                                             const u16* __restrict__ Wt1,
                                             u16* __restrict__ h1p,
                                             float* __restrict__ es1,
                                             float* __restrict__ ed1) {
    __shared__ __align__(16) s16 As[128 * 128];
    __shared__ __align__(16) s16 Bs[BN1 * 128];
    int t = threadIdx.x;
    int row0 = blockIdx.x * 128;
    #pragma unroll
    for (int i = 0; i < 16; ++i) {
        int c = t + i * 256;
        int r = c >> 5, k0 = (c & 31) * 4;
        float4 v = make_float4(0.f, 0.f, 0.f, 0.f);
        int row = row0 + r;
        if (row < NN) v = *(const float4*)&x[(size_t)row * 128 + k0];
        u16 pk[4] = {f2bf(v.x), f2bf(v.y), f2bf(v.z), f2bf(v.w)};
        int byte = (r * 256 + k0 * 2) ^ ((r & 7) << 4);
        *(uint2*)((char*)As + byte) = *(uint2*)pk;
    }
    #pragma unroll
    for (int i = 0; i < 9; ++i) {
        int c = t + i * 256;
        int n = c >> 4, k0 = (c & 15) * 8;
        uint4 v = *(const uint4*)&Wt1[n * 128 + k0];
        int byte = (n * 256 + k0 * 2) ^ ((n & 7) << 4);
        *(uint4*)((char*)Bs + byte) = v;
    }
    __syncthreads();
    int wave = t >> 6, lane = t & 63;
    int lr = lane & 15, lq = lane >> 4;
    int wrow = wave * 32;
    f32x4 acc[2][9];
    #pragma unroll
    for (int a = 0; a < 2; ++a)
        #pragma unroll
        for (int b = 0; b < 9; ++b) acc[a][b] = (f32x4){0.f, 0.f, 0.f, 0.f};
    #pragma unroll
    for (int ks = 0; ks < 4; ++ks) {
        int kb = ks * 32 + lq * 8;
        bf16x8 af[2];
        #pragma unroll
        for (int rb = 0; rb < 2; ++rb) {
            int r = wrow + rb * 16 + lr;
            int byte = (r * 256 + kb * 2) ^ ((r & 7) << 4);
            af[rb] = *(bf16x8*)((char*)As + byte);
        }
        #pragma unroll
        for (int cb = 0; cb < 9; ++cb) {
            int n = cb * 16 + lr;
            int byte = (n * 256 + kb * 2) ^ ((n & 7) << 4);
            bf16x8 bfr = *(bf16x8*)((char*)Bs + byte);
            acc[0][cb] = __builtin_amdgcn_mfma_f32_16x16x32_bf16(af[0], bfr, acc[0][cb], 0, 0, 0);
            acc[1][cb] = __builtin_amdgcn_mfma_f32_16x16x32_bf16(af[1], bfr, acc[1][cb], 0, 0, 0);
        }
    }
    #pragma unroll
    for (int rb = 0; rb < 2; ++rb) {
        #pragma unroll
        for (int cb = 0; cb < 9; ++cb) {
            #pragma unroll
            for (int r = 0; r < 4; ++r) {
                int row = row0 + wrow + rb * 16 + lq * 4 + r;
                int col = cb * 16 + lr;
                if (row < NN) {
                    float v = acc[rb][cb][r];
                    if (col < 128) {
                        int p = col >> 4, cc = col & 15;
                        h1p[(size_t)p * NN * 16 + (size_t)row * 16 + cc] = f2bf(v);
                    }
                    else if (col < 132) es1[row * 4 + (col - 128)] = v;
                    else if (col < 136) ed1[row * 4 + (col - 132)] = v;
                }
            }
        }
    }
}

// MFMA GEMM layer 2: h2b[NN,64] bf16 (col 40 = es2 bf16, 41..63 zero) + ed2[NN] fp32.
__global__ __launch_bounds__(256) void k_mm2(const u16* __restrict__ hbnb,
                                             const u16* __restrict__ Wt2,
                                             u16* __restrict__ h2b,
                                             float* __restrict__ ed2) {
    __shared__ __align__(16) s16 As[128 * 128];
    __shared__ __align__(16) s16 Bs[BN2 * 128];
    int t = threadIdx.x;
    int row0 = blockIdx.x * 128;
    #pragma unroll
    for (int i = 0; i < 8; ++i) {
        int c = t + i * 256;
        int r = c >> 4, k0 = (c & 15) * 8;
        uint4 v = make_uint4(0, 0, 0, 0);
        int row = row0 + r;
        if (row < NN) v = *(const uint4*)&hbnb[(size_t)row * 128 + k0];
        int byte = (r * 256 + k0 * 2) ^ ((r & 7) << 4);
        *(uint4*)((char*)As + byte) = v;
    }
    #pragma unroll
    for (int i = 0; i < 3; ++i) {
        int c = t + i * 256;
        int n = c >> 4, k0 = (c & 15) * 8;
        uint4 v = *(const uint4*)&Wt2[n * 128 + k0];
        int byte = (n * 256 + k0 * 2) ^ ((n & 7) << 4);
        *(uint4*)((char*)Bs + byte) = v;
    }
    __syncthreads();
    int wave = t >> 6, lane = t & 63;
    int lr = lane & 15, lq = lane >> 4;
    int wrow = wave * 32;
    f32x4 acc[2][3];
    #pragma unroll
    for (int a = 0; a < 2; ++a)
        #pragma unroll
        for (int b = 0; b < 3; ++b) acc[a][b] = (f32x4){0.f, 0.f, 0.f, 0.f};
    #pragma unroll
    for (int ks = 0; ks < 4; ++ks) {
        int kb = ks * 32 + lq * 8;
        bf16x8 af[2];
        #pragma unroll
        for (int rb = 0; rb < 2; ++rb) {
            int r = wrow + rb * 16 + lr;
            int byte = (r * 256 + kb * 2) ^ ((r & 7) << 4);
            af[rb] = *(bf16x8*)((char*)As + byte);
        }
        #pragma unroll
        for (int cb = 0; cb < 3; ++cb) {
            int n = cb * 16 + lr;
            int byte = (n * 256 + kb * 2) ^ ((n & 7) << 4);
            bf16x8 bfr = *(bf16x8*)((char*)Bs + byte);
            acc[0][cb] = __builtin_amdgcn_mfma_f32_16x16x32_bf16(af[0], bfr, acc[0][cb], 0, 0, 0);
            acc[1][cb] = __builtin_amdgcn_mfma_f32_16x16x32_bf16(af[1], bfr, acc[1][cb], 0, 0, 0);
        }
    }
    #pragma unroll
    for (int rb = 0; rb < 2; ++rb) {
        #pragma unroll
        for (int cb = 0; cb < 3; ++cb) {
            #pragma unroll
            for (int r = 0; r < 4; ++r) {
                int row = row0 + wrow + rb * 16 + lq * 4 + r;
                int col = cb * 16 + lr;
                if (row < NN) {
                    float v = acc[rb][cb][r];
                    if (col <= 40) {
                        h2b[(size_t)row * 64 + col] = f2bf(v);
                    } else {
                        if (col == 41) ed2[row] = v;
                        h2b[(size_t)row * 64 + col] = 0;
                    }
                }
            }
        }
    }
}

// layer-1 aggregation, panel-partitioned: panel = blockIdx.x & 7 (XCD-aligned),
// 2 lanes/edge x uint4 over the 16-col panel, 64 edges/iter (2 loads in flight)
__global__ __launch_bounds__(256) void k_agg1(
        const u16* __restrict__ h1p, const float* __restrict__ es,
        const float* __restrict__ ed, const int* __restrict__ offsets,
        const u16* __restrict__ ssrc, const float* __restrict__ b1,
        const float* __restrict__ gamma, const float* __restrict__ beta,
        const float* __restrict__ mean, const float* __restrict__ var,
        u16* __restrict__ hbnb) {
    __shared__ float wlds[4][64];
    int wv = threadIdx.x >> 6;
    int panel = blockIdx.x & 7;
    int node = (blockIdx.x >> 3) * 4 + wv;
    if (node >= NN) return;
    int l = threadIdx.x & 63;
    int g = l >> 1;          // edge slot 0..31
    int c2 = l & 1;          // col half (8 cols)
    int head = panel >> 1;
    int p0 = offsets[node], p1 = offsets[node + 1];
    float edh = ed[node * 4 + head];
    const u16* hp = h1p + (size_t)panel * NN * 16;
    float swacc = 0.f;
    float acc[8];
    #pragma unroll
    for (int i = 0; i < 8; ++i) acc[i] = 0.f;
    for (int base = p0; base < p1; base += 64) {
        int cnt = min(64, p1 - base);
        int myidx = (l < cnt) ? (int)ssrc[base + l] : 0;
        float w = 0.f;
        if (l < cnt) {
            float e = es[myidx * 4 + head] + edh;
            e = e > 0.f ? e : LEAKY * e;
            w = __expf(e);
        }
        wlds[wv][l] = w;
        swacc += w;
        __builtin_amdgcn_wave_barrier();
        for (int j = 0; j < cnt; j += 64) {
            int e0 = j + g, e1 = j + 32 + g;
            int c0v = min(e0, cnt - 1), c1v = min(e1, cnt - 1);
            int s0 = __shfl(myidx, c0v);
            int s1 = __shfl(myidx, c1v);
            float x0 = (e0 < cnt) ? wlds[wv][c0v] : 0.f;
            float x1 = (e1 < cnt) ? wlds[wv][c1v] : 0.f;
            uint4 r0 = *(const uint4*)&hp[(size_t)s0 * 16 + c2 * 8];
            uint4 r1 = *(const uint4*)&hp[(size_t)s1 * 16 + c2 * 8];
            acc[0] = fmaf(x0, bf2f_lo(r0.x), acc[0]);
            acc[1] = fmaf(x0, bf2f_hi(r0.x), acc[1]);
            acc[2] = fmaf(x0, bf2f_lo(r0.y), acc[2]);
            acc[3] = fmaf(x0, bf2f_hi(r0.y), acc[3]);
            acc[4] = fmaf(x0, bf2f_lo(r0.z), acc[4]);
            acc[5] = fmaf(x0, bf2f_hi(r0.z), acc[5]);
            acc[6] = fmaf(x0, bf2f_lo(r0.w), acc[6]);
            acc[7] = fmaf(x0, bf2f_hi(r0.w), acc[7]);
            acc[0] = fmaf(x1, bf2f_lo(r1.x), acc[0]);
            acc[1] = fmaf(x1, bf2f_hi(r1.x), acc[1]);
            acc[2] = fmaf(x1, bf2f_lo(r1.y), acc[2]);
            acc[3] = fmaf(x1, bf2f_hi(r1.y), acc[3]);
            acc[4] = fmaf(x1, bf2f_lo(r1.z), acc[4]);
            acc[5] = fmaf(x1, bf2f_hi(r1.z), acc[5]);
            acc[6] = fmaf(x1, bf2f_lo(r1.w), acc[6]);
            acc[7] = fmaf(x1, bf2f_hi(r1.w), acc[7]);
        }
    }
    // fold the 32 edge slots (lanes sharing c2 differ in bits 1..5)
    #pragma unroll
    for (int i = 0; i < 8; ++i) {
        acc[i] += __shfl_xor(acc[i], 2);
        acc[i] += __shfl_xor(acc[i], 4);
        acc[i] += __shfl_xor(acc[i], 8);
        acc[i] += __shfl_xor(acc[i], 16);
        acc[i] += __shfl_xor(acc[i], 32);
    }
    // denominator for this head: reduce all 64 lanes
    float s = swacc;
    #pragma unroll
    for (int off = 1; off < 64; off <<= 1) s += __shfl_xor(s, off);
    if (l < 2) {
        float inv = 1.f / s;
        int c0 = panel * 16 + c2 * 8;
        float4 b1a = *(const float4*)&b1[c0],    b1b = *(const float4*)&b1[c0 + 4];
        float4 mna = *(const float4*)&mean[c0],  mnb = *(const float4*)&mean[c0 + 4];
        float4 vra = *(const float4*)&var[c0],   vrb = *(const float4*)&var[c0 + 4];
        float4 gma = *(const float4*)&gamma[c0], gmb = *(const float4*)&gamma[c0 + 4];
        float4 bta = *(const float4*)&beta[c0],  btb = *(const float4*)&beta[c0 + 4];
        float bv[8] = {b1a.x, b1a.y, b1a.z, b1a.w, b1b.x, b1b.y, b1b.z, b1b.w};
        float mn[8] = {mna.x, mna.y, mna.z, mna.w, mnb.x, mnb.y, mnb.z, mnb.w};
        float vr[8] = {vra.x, vra.y, vra.z, vra.w, vrb.x, vrb.y, vrb.z, vrb.w};
        float gm[8] = {gma.x, gma.y, gma.z, gma.w, gmb.x, gmb.y, gmb.z, gmb.w};
        float bt[8] = {bta.x, bta.y, bta.z, bta.w, btb.x, btb.y, btb.z, btb.w};
        u16 pk[8];
        #pragma unroll
        for (int i = 0; i < 8; ++i) {
            float o = acc[i] * inv + bv[i];
            o = (o - mn[i]) * rsqrtf(vr[i] + BN_EPS) * gm[i] + bt[i];
            o = o > 0.f ? o : __expf(o) - 1.f;
            pk[i] = f2bf(o);
        }
        *(uint4*)&hbnb[(size_t)node * 128 + c0] = *(uint4*)pk;
    }
}

// layer-2 aggregation: wide uint4 gather over bf16 h2b; es2 folded into
// h2b col 40; 4 loads in flight -> 32 edges/iter; distributed log_softmax
__global__ __launch_bounds__(256) void k_agg2(
        const u16* __restrict__ h2b, const float* __restrict__ ed,
        const int* __restrict__ offsets, const u16* __restrict__ ssrc,
        const float* __restrict__ b2, float* __restrict__ out) {
    __shared__ float wlds[4][64];
    int wv = threadIdx.x >> 6;
    int node = blockIdx.x * 4 + wv;
    if (node >= NN) return;
    int l = threadIdx.x & 63;
    int g = l >> 3;      // edge slot 0..7
    int c8 = l & 7;      // column block: cols c8*8 .. c8*8+7
    int p0 = offsets[node], p1 = offsets[node + 1];
    float edv = ed[node];
    float swacc = 0.f;
    float acc[8];
    #pragma unroll
    for (int i = 0; i < 8; ++i) acc[i] = 0.f;
    for (int base = p0; base < p1; base += 64) {
        int cnt = min(64, p1 - base);
        int myidx = (l < cnt) ? (int)ssrc[base + l] : 0;
        float mw = 0.f;
        if (l < cnt) {
            float esv = bf2f((u32)h2b[(size_t)myidx * 64 + 40]);
            float e = esv + edv;
            e = e > 0.f ? e : LEAKY * e;
            mw = __expf(e);
        }
        wlds[wv][l] = mw;
        swacc += mw;
        __builtin_amdgcn_wave_barrier();
        for (int j = 0; j < cnt; j += 32) {
            int e0 = j + g, e1 = j + 8 + g, e2 = j + 16 + g, e3 = j + 24 + g;
            int c0v = min(e0, cnt - 1), c1v = min(e1, cnt - 1);
            int c2v = min(e2, cnt - 1), c3v = min(e3, cnt - 1);
            int s0 = __shfl(myidx, c0v);
            int s1 = __shfl(myidx, c1v);
            int s2 = __shfl(myidx, c2v);
            int s3 = __shfl(myidx, c3v);
            float x0 = (e0 < cnt) ? wlds[wv][c0v] : 0.f;
            float x1 = (e1 < cnt) ? wlds[wv][c1v] : 0.f;
            float x2 = (e2 < cnt) ? wlds[wv][c2v] : 0.f;
            float x3 = (e3 < cnt) ? wlds[wv][c3v] : 0.f;
            uint4 r0 = *(const uint4*)&h2b[(size_t)s0 * 64 + c8 * 8];
            uint4 r1 = *(const uint4*)&h2b[(size_t)s1 * 64 + c8 * 8];
            uint4 r2 = *(const uint4*)&h2b[(size_t)s2 * 64 + c8 * 8];
            uint4 r3 = *(const uint4*)&h2b[(size_t)s3 * 64 + c8 * 8];
            acc[0] = fmaf(x0, bf2f_lo(r0.x), acc[0]);
            acc[1] = fmaf(x0, bf2f_hi(r0.x), acc[1]);
            acc[2] = fmaf(x0, bf2f_lo(r0.y), acc[2]);
            acc[3] = fmaf(x0, bf2f_hi(r0.y), acc[3]);
            acc[4] = fmaf(x0, bf2f_lo(r0.z), acc[4]);
            acc[5] = fmaf(x0, bf2f_hi(r0.z), acc[5]);
            acc[6] = fmaf(x0, bf2f_lo(r0.w), acc[6]);
            acc[7] = fmaf(x0, bf2f_hi(r0.w), acc[7]);
            acc[0] = fmaf(x1, bf2f_lo(r1.x), acc[0]);
            acc[1] = fmaf(x1, bf2f_hi(r1.x), acc[1]);
            acc[2] = fmaf(x1, bf2f_lo(r1.y), acc[2]);
            acc[3] = fmaf(x1, bf2f_hi(r1.y), acc[3]);
            acc[4] = fmaf(x1, bf2f_lo(r1.z), acc[4]);
            acc[5] = fmaf(x1, bf2f_hi(r1.z), acc[5]);
            acc[6] = fmaf(x1, bf2f_lo(r1.w), acc[6]);
            acc[7] = fmaf(x1, bf2f_hi(r1.w), acc[7]);
            acc[0] = fmaf(x2, bf2f_lo(r2.x), acc[0]);
            acc[1] = fmaf(x2, bf2f_hi(r2.x), acc[1]);
            acc[2] = fmaf(x2, bf2f_lo(r2.y), acc[2]);
            acc[3] = fmaf(x2, bf2f_hi(r2.y), acc[3]);
            acc[4] = fmaf(x2, bf2f_lo(r2.z), acc[4]);
            acc[5] = fmaf(x2, bf2f_hi(r2.z), acc[5]);
            acc[6] = fmaf(x2, bf2f_lo(r2.w), acc[6]);
            acc[7] = fmaf(x2, bf2f_hi(r2.w), acc[7]);
            acc[0] = fmaf(x3, bf2f_lo(r3.x), acc[0]);
            acc[1] = fmaf(x3, bf2f_hi(r3.x), acc[1]);
            acc[2] = fmaf(x3, bf2f_lo(r3.y), acc[2]);
            acc[3] = fmaf(x3, bf2f_hi(r3.y), acc[3]);
            acc[4] = fmaf(x3, bf2f_lo(r3.z), acc[4]);
            acc[5] = fmaf(x3, bf2f_hi(r3.z), acc[5]);
            acc[6] = fmaf(x3, bf2f_lo(r3.w), acc[6]);
            acc[7] = fmaf(x3, bf2f_hi(r3.w), acc[7]);
        }
    }
    #pragma unroll
    for (int i = 0; i < 8; ++i) {
        acc[i] += __shfl_xor(acc[i], 8);
        acc[i] += __shfl_xor(acc[i], 16);
        acc[i] += __shfl_xor(acc[i], 32);
    }
    float s = swacc;
    #pragma unroll
    for (int off = 1; off < 64; off <<= 1) s += __shfl_xor(s, off);
    float inv = 1.f / s;
    bool valid = (c8 < 5);
    int c0 = c8 * 8;
    float v[8];
    float m8 = -1e30f;
    if (valid) {
        float4 b2a = *(const float4*)&b2[c0];
        float4 b2b = *(const float4*)&b2[c0 + 4];
        float bv[8] = {b2a.x, b2a.y, b2a.z, b2a.w, b2b.x, b2b.y, b2b.z, b2b.w};
        #pragma unroll
        for (int i = 0; i < 8; ++i) {
            v[i] = acc[i] * inv + bv[i];
            m8 = fmaxf(m8, v[i]);
        }
    }
    m8 = fmaxf(m8, __shfl_xor(m8, 1));
    m8 = fmaxf(m8, __shfl_xor(m8, 2));
    m8 = fmaxf(m8, __shfl_xor(m8, 4));
    float ex = 0.f;
    if (valid) {
        #pragma unroll
        for (int i = 0; i < 8; ++i) ex += __expf(v[i] - m8);
    }
    ex += __shfl_xor(ex, 1);
    ex += __shfl_xor(ex, 2);
    ex += __shfl_xor(ex, 4);
    if (g == 0 && valid) {
        float lg = m8 + __logf(ex);
        float4 o0 = make_float4(v[0] - lg, v[1] - lg, v[2] - lg, v[3] - lg);
        float4 o1 = make_float4(v[4] - lg, v[5] - lg, v[6] - lg, v[7] - lg);
        *(float4*)&out[(size_t)node * 40 + c0] = o0;
        *(float4*)&out[(size_t)node * 40 + c0 + 4] = o1;
    }
}

extern "C" void kernel_launch(void* const* d_in, const int* in_sizes, int n_in,
                              void* d_out, int out_size, void* d_ws, size_t ws_size,
                              hipStream_t stream) {
    const float* x   = (const float*)d_in[0];
    const int*   ei  = (const int*)d_in[1];
    const float* W1  = (const float*)d_in[2];
    const float* a1s = (const float*)d_in[3];
    const float* a1d = (const float*)d_in[4];
    const float* b1  = (const float*)d_in[5];
    const float* bng = (const float*)d_in[6];
    const float* bnb = (const float*)d_in[7];
    const float* bnm = (const float*)d_in[8];
    const float* bnv = (const float*)d_in[9];
    const float* W2  = (const float*)d_in[10];
    const float* a2s = (const float*)d_in[11];
    const float* a2d = (const float*)d_in[12];
    const float* b2  = (const float*)d_in[13];
    float* out = (float*)d_out;

    char* ws = (char*)d_ws;
    size_t off = 0;
    auto alloc = [&](size_t bytes) -> void* {
        void* p = ws + off;
        off = (off + bytes + 255) & ~(size_t)255;
        return p;
    };
    int*   cntb     = (int*)alloc((size_t)NB * NBB * 4);
    int*   excl     = (int*)alloc((size_t)NB * NBB * 4);
    int*   offsets  = (int*)alloc((size_t)(NN + 1) * 4);
    u32*   packed   = (u32*)alloc((size_t)ETOT * 4);
    u16*   ssrc     = (u16*)alloc((size_t)ETOT * 2);
    u16*   Wt1      = (u16*)alloc((size_t)BN1 * 128 * 2);
    u16*   Wt2      = (u16*)alloc((size_t)BN2 * 128 * 2);
    u16*   h1p      = (u16*)alloc((size_t)NN * 128 * 2);
    float* es1      = (float*)alloc((size_t)NN * 4 * 4);
    float* ed1      = (float*)alloc((size_t)NN * 4 * 4);
    u16*   hbnb     = (u16*)alloc((size_t)NN * 128 * 2);
    u16*   h2b      = (u16*)alloc((size_t)NN * 64 * 2);
    float* ed2      = (float*)alloc((size_t)NN * 4);

    k_binA_prep<<<NBB + PREPB, 256, 0, stream>>>(ei, cntb, W1, a1s, a1d,
                                                 W2, a2s, a2d, Wt1, Wt2);
    k_scanONE<<<1, 1024, 0, stream>>>(cntb, excl);
    k_binB<<<NBB, 256, 0, stream>>>(ei, excl, packed);
    k_binC<<<NB, 256, 0, stream>>>(packed, excl, offsets, ssrc);
    k_mm1<<<(NN + 127) / 128, 256, 0, stream>>>(x, Wt1, h1p, es1, ed1);
    k_agg1<<<((NN + 3) / 4) * 8, 256, 0, stream>>>(h1p, es1, ed1, offsets, ssrc,
                                                   b1, bng, bnb, bnm, bnv, hbnb);
    k_mm2<<<(NN + 127) / 128, 256, 0, stream>>>(hbnb, Wt2, h2b, ed2);
    k_agg2<<<(NN + 3) / 4, 256, 0, stream>>>(h2b, ed2, offsets, ssrc, b2, out);
}

// Round 15
// 137.006 us; speedup vs baseline: 2.2093x; 2.2093x over previous
//
#include <hip/hip_runtime.h>
#include <hip/hip_bf16.h>
#include <math.h>

#define NN 50000
#define NE 800000
#define ETOT (NE + NN)
#define LEAKY 0.2f
#define BN_EPS 1e-5f

#define NB 256      // dst buckets
#define BSZ 196     // nodes per bucket (256*196 = 50176 >= NN)
#define NBB 128     // binning blocks
#define EPB ((ETOT + NBB - 1) / NBB)
#define PREPB 80    // prep blocks appended to binA grid

#define BN1 144   // 128 h1 cols + 4 es + 4 ed + 8 pad
#define BN2 48    // 40 h2 cols + es2 + ed2 + 6 pad

typedef unsigned short u16;
typedef unsigned int u32;
typedef short s16;
typedef __attribute__((ext_vector_type(8))) short bf16x8;
typedef __attribute__((ext_vector_type(4))) float f32x4;

__device__ __forceinline__ float bf2f(u32 u) {
    union { u32 i; float f; } x; x.i = u << 16; return x.f;
}
__device__ __forceinline__ float bf2f_lo(u32 u) {
    union { u32 i; float f; } x; x.i = u << 16; return x.f;
}
__device__ __forceinline__ float bf2f_hi(u32 u) {
    union { u32 i; float f; } x; x.i = u & 0xffff0000u; return x.f;
}
__device__ __forceinline__ u16 f2bf(float f) {
    __hip_bfloat16 b = __float2bfloat16(f);
    return *reinterpret_cast<u16*>(&b);
}

// ---- CSR build pass A fused with weight prep ----
__global__ __launch_bounds__(256) void k_binA_prep(
        const int* __restrict__ ei, int* __restrict__ cnt,
        const float* __restrict__ W1, const float* __restrict__ a1s,
        const float* __restrict__ a1d, const float* __restrict__ W2,
        const float* __restrict__ a2s, const float* __restrict__ a2d,
        u16* __restrict__ Wt1, u16* __restrict__ Wt2) {
    if (blockIdx.x < NBB) {
        __shared__ int hist[NB];
        int t = threadIdx.x;
        for (int i = t; i < NB; i += 256) hist[i] = 0;
        __syncthreads();
        int e0 = blockIdx.x * EPB, e1 = min(e0 + EPB, ETOT);
        for (int e = e0 + t; e < e1; e += 256) {
            int dst = (e < NE) ? ei[NE + e] : (e - NE);
            atomicAdd(&hist[dst / BSZ], 1);
        }
        __syncthreads();
        for (int b = t; b < NB; b += 256) cnt[b * NBB + blockIdx.x] = hist[b];
    } else {
        int tid = (blockIdx.x - NBB) * 256 + threadIdx.x;
        int nth = PREPB * 256;
        for (int idx = tid; idx < BN1 * 128; idx += nth) {
            int n = idx >> 7, k = idx & 127;
            float v = 0.f;
            if (n < 128) v = W1[k * 128 + n];
            else if (n < 132) {
                int h = n - 128; float s = 0.f;
                for (int c = 0; c < 32; ++c) s += W1[k * 128 + h * 32 + c] * a1s[h * 32 + c];
                v = s;
            } else if (n < 136) {
                int h = n - 132; float s = 0.f;
                for (int c = 0; c < 32; ++c) s += W1[k * 128 + h * 32 + c] * a1d[h * 32 + c];
                v = s;
            }
            Wt1[idx] = f2bf(v);
        }
        for (int idx = tid; idx < BN2 * 128; idx += nth) {
            int n = idx >> 7, k = idx & 127;
            float v = 0.f;
            if (n < 40) v = W2[k * 40 + n];
            else if (n == 40) { float s = 0.f; for (int c = 0; c < 40; ++c) s += W2[k * 40 + c] * a2s[c]; v = s; }
            else if (n == 41) { float s = 0.f; for (int c = 0; c < 40; ++c) s += W2[k * 40 + c] * a2d[c]; v = s; }
            Wt2[idx] = f2bf(v);
        }
    }
}

// single-kernel exclusive scan of exactly NB*NBB = 32768 ints
__global__ __launch_bounds__(1024) void k_scanONE(const int* __restrict__ in,
                                                  int* __restrict__ out) {
    __shared__ int sums[1024];
    int t = threadIdx.x;
    int4 loc[8];
    const int4* ip = (const int4*)(in + t * 32);
    int s = 0;
    #pragma unroll
    for (int i = 0; i < 8; ++i) {
        loc[i] = ip[i];
        s += loc[i].x + loc[i].y + loc[i].z + loc[i].w;
    }
    sums[t] = s;
    __syncthreads();
    for (int off = 1; off < 1024; off <<= 1) {
        int u = (t >= off) ? sums[t - off] : 0;
        __syncthreads();
        sums[t] += u;
        __syncthreads();
    }
    int run = (t == 0) ? 0 : sums[t - 1];
    int* op = out + t * 32;
    #pragma unroll
    for (int i = 0; i < 8; ++i) {
        op[i * 4 + 0] = run; run += loc[i].x;
        op[i * 4 + 1] = run; run += loc[i].y;
        op[i * 4 + 2] = run; run += loc[i].z;
        op[i * 4 + 3] = run; run += loc[i].w;
    }
}

__global__ __launch_bounds__(256) void k_binB(const int* __restrict__ ei,
                                              const int* __restrict__ excl,
                                              u32* __restrict__ packed) {
    __shared__ int cur[NB];
    int t = threadIdx.x;
    for (int b = t; b < NB; b += 256) cur[b] = excl[b * NBB + blockIdx.x];
    __syncthreads();
    int e0 = blockIdx.x * EPB, e1 = min(e0 + EPB, ETOT);
    for (int e = e0 + t; e < e1; e += 256) {
        int src, dst;
        if (e < NE) { src = ei[e]; dst = ei[NE + e]; }
        else        { src = e - NE; dst = e - NE; }
        int pos = atomicAdd(&cur[dst / BSZ], 1);
        packed[pos] = ((u32)src << 16) | (u32)dst;
    }
}

__global__ __launch_bounds__(256) void k_binC(const u32* __restrict__ packed,
                                              const int* __restrict__ excl,
                                              int* __restrict__ offsets,
                                              u16* __restrict__ ssrc) {
    __shared__ int hist[256];
    __shared__ int sc[256];
    __shared__ int cur[256];
    int b = blockIdx.x, t = threadIdx.x;
    int n0 = b * BSZ;
    int base = excl[b * NBB];
    int next = (b < NB - 1) ? excl[(b + 1) * NBB] : ETOT;
    int total = next - base;
    hist[t] = 0;
    __syncthreads();
    for (int i = t; i < total; i += 256) {
        int dst = (int)(packed[base + i] & 0xffffu);
        atomicAdd(&hist[dst - n0], 1);
    }
    __syncthreads();
    int v = hist[t];
    sc[t] = v;
    __syncthreads();
    #pragma unroll
    for (int off = 1; off < 256; off <<= 1) {
        int u = (t >= off) ? sc[t - off] : 0;
        __syncthreads();
        sc[t] += u;
        __syncthreads();
    }
    int exl = sc[t] - v;
    int node = n0 + t;
    if (t <= BSZ && node <= NN) {
        if (t < BSZ || node == NN) offsets[node] = base + exl;
    }
    cur[t] = exl;
    __syncthreads();
    for (int i = t; i < total; i += 256) {
        u32 pv = packed[base + i];
        int dst = (int)(pv & 0xffffu);
        int pos = atomicAdd(&cur[dst - n0], 1);
        ssrc[base + pos] = (u16)(pv >> 16);
    }
}

// MFMA GEMM layer 1: h1b[NN,128] bf16 + es1/ed1[NN,4] fp32, from x fp32.
__global__ __launch_bounds__(256) void k_mm1(const float* __restrict__ x,
                                             const u16* __restrict__ Wt1,
                                             u16* __restrict__ h1b,
                                             float* __restrict__ es1,
                                             float* __restrict__ ed1) {
    __shared__ __align__(16) s16 As[128 * 128];
    __shared__ __align__(16) s16 Bs[BN1 * 128];
    int t = threadIdx.x;
    int row0 = blockIdx.x * 128;
    #pragma unroll
    for (int i = 0; i < 16; ++i) {
        int c = t + i * 256;
        int r = c >> 5, k0 = (c & 31) * 4;
        float4 v = make_float4(0.f, 0.f, 0.f, 0.f);
        int row = row0 + r;
        if (row < NN) v = *(const float4*)&x[(size_t)row * 128 + k0];
        u16 pk[4] = {f2bf(v.x), f2bf(v.y), f2bf(v.z), f2bf(v.w)};
        int byte = (r * 256 + k0 * 2) ^ ((r & 7) << 4);
        *(uint2*)((char*)As + byte) = *(uint2*)pk;
    }
    #pragma unroll
    for (int i = 0; i < 9; ++i) {
        int c = t + i * 256;
        int n = c >> 4, k0 = (c & 15) * 8;
        uint4 v = *(const uint4*)&Wt1[n * 128 + k0];
        int byte = (n * 256 + k0 * 2) ^ ((n & 7) << 4);
        *(uint4*)((char*)Bs + byte) = v;
    }
    __syncthreads();
    int wave = t >> 6, lane = t & 63;
    int lr = lane & 15, lq = lane >> 4;
    int wrow = wave * 32;
    f32x4 acc[2][9];
    #pragma unroll
    for (int a = 0; a < 2; ++a)
        #pragma unroll
        for (int b = 0; b < 9; ++b) acc[a][b] = (f32x4){0.f, 0.f, 0.f, 0.f};
    #pragma unroll
    for (int ks = 0; ks < 4; ++ks) {
        int kb = ks * 32 + lq * 8;
        bf16x8 af[2];
        #pragma unroll
        for (int rb = 0; rb < 2; ++rb) {
            int r = wrow + rb * 16 + lr;
            int byte = (r * 256 + kb * 2) ^ ((r & 7) << 4);
            af[rb] = *(bf16x8*)((char*)As + byte);
        }
        #pragma unroll
        for (int cb = 0; cb < 9; ++cb) {
            int n = cb * 16 + lr;
            int byte = (n * 256 + kb * 2) ^ ((n & 7) << 4);
            bf16x8 bfr = *(bf16x8*)((char*)Bs + byte);
            acc[0][cb] = __builtin_amdgcn_mfma_f32_16x16x32_bf16(af[0], bfr, acc[0][cb], 0, 0, 0);
            acc[1][cb] = __builtin_amdgcn_mfma_f32_16x16x32_bf16(af[1], bfr, acc[1][cb], 0, 0, 0);
        }
    }
    #pragma unroll
    for (int rb = 0; rb < 2; ++rb) {
        #pragma unroll
        for (int cb = 0; cb < 9; ++cb) {
            #pragma unroll
            for (int r = 0; r < 4; ++r) {
                int row = row0 + wrow + rb * 16 + lq * 4 + r;
                int col = cb * 16 + lr;
                if (row < NN) {
                    float v = acc[rb][cb][r];
                    if (col < 128) h1b[(size_t)row * 128 + col] = f2bf(v);
                    else if (col < 132) es1[row * 4 + (col - 128)] = v;
                    else if (col < 136) ed1[row * 4 + (col - 132)] = v;
                }
            }
        }
    }
}

// MFMA GEMM layer 2: h2b[NN,64] bf16 (col 40 = es2 bf16, 41..63 zero) + ed2[NN] fp32.
__global__ __launch_bounds__(256) void k_mm2(const u16* __restrict__ hbnb,
                                             const u16* __restrict__ Wt2,
                                             u16* __restrict__ h2b,
                                             float* __restrict__ ed2) {
    __shared__ __align__(16) s16 As[128 * 128];
    __shared__ __align__(16) s16 Bs[BN2 * 128];
    int t = threadIdx.x;
    int row0 = blockIdx.x * 128;
    #pragma unroll
    for (int i = 0; i < 8; ++i) {
        int c = t + i * 256;
        int r = c >> 4, k0 = (c & 15) * 8;
        uint4 v = make_uint4(0, 0, 0, 0);
        int row = row0 + r;
        if (row < NN) v = *(const uint4*)&hbnb[(size_t)row * 128 + k0];
        int byte = (r * 256 + k0 * 2) ^ ((r & 7) << 4);
        *(uint4*)((char*)As + byte) = v;
    }
    #pragma unroll
    for (int i = 0; i < 3; ++i) {
        int c = t + i * 256;
        int n = c >> 4, k0 = (c & 15) * 8;
        uint4 v = *(const uint4*)&Wt2[n * 128 + k0];
        int byte = (n * 256 + k0 * 2) ^ ((n & 7) << 4);
        *(uint4*)((char*)Bs + byte) = v;
    }
    __syncthreads();
    int wave = t >> 6, lane = t & 63;
    int lr = lane & 15, lq = lane >> 4;
    int wrow = wave * 32;
    f32x4 acc[2][3];
    #pragma unroll
    for (int a = 0; a < 2; ++a)
        #pragma unroll
        for (int b = 0; b < 3; ++b) acc[a][b] = (f32x4){0.f, 0.f, 0.f, 0.f};
    #pragma unroll
    for (int ks = 0; ks < 4; ++ks) {
        int kb = ks * 32 + lq * 8;
        bf16x8 af[2];
        #pragma unroll
        for (int rb = 0; rb < 2; ++rb) {
            int r = wrow + rb * 16 + lr;
            int byte = (r * 256 + kb * 2) ^ ((r & 7) << 4);
            af[rb] = *(bf16x8*)((char*)As + byte);
        }
        #pragma unroll
        for (int cb = 0; cb < 3; ++cb) {
            int n = cb * 16 + lr;
            int byte = (n * 256 + kb * 2) ^ ((n & 7) << 4);
            bf16x8 bfr = *(bf16x8*)((char*)Bs + byte);
            acc[0][cb] = __builtin_amdgcn_mfma_f32_16x16x32_bf16(af[0], bfr, acc[0][cb], 0, 0, 0);
            acc[1][cb] = __builtin_amdgcn_mfma_f32_16x16x32_bf16(af[1], bfr, acc[1][cb], 0, 0, 0);
        }
    }
    #pragma unroll
    for (int rb = 0; rb < 2; ++rb) {
        #pragma unroll
        for (int cb = 0; cb < 3; ++cb) {
            #pragma unroll
            for (int r = 0; r < 4; ++r) {
                int row = row0 + wrow + rb * 16 + lq * 4 + r;
                int col = cb * 16 + lr;
                if (row < NN) {
                    float v = acc[rb][cb][r];
                    if (col <= 40) {
                        h2b[(size_t)row * 64 + col] = f2bf(v);
                    } else {
                        if (col == 41) ed2[row] = v;
                        h2b[(size_t)row * 64 + col] = 0;
                    }
                }
            }
        }
    }
}

// layer-1 aggregation: lane-parallel weight phase + wide uint4 gather
// (16 lanes/edge, 4 edges per wave-load, 2 loads in flight) [R12 proven: 45.4us]
__global__ __launch_bounds__(256) void k_agg1(
        const u16* __restrict__ h1b, const float* __restrict__ es,
        const float* __restrict__ ed, const int* __restrict__ offsets,
        const u16* __restrict__ ssrc, const float* __restrict__ b1,
        const float* __restrict__ gamma, const float* __restrict__ beta,
        const float* __restrict__ mean, const float* __restrict__ var,
        u16* __restrict__ hbnb) {
    __shared__ float wlds[4][64][4];   // [wave][edge][head]
    int wv = threadIdx.x >> 6;
    int node = blockIdx.x * 4 + wv;
    if (node >= NN) return;
    int l = threadIdx.x & 63;
    int g = l >> 4;          // edge-in-group 0..3
    int c16 = l & 15;        // 16-byte column block
    int h = c16 >> 2;        // head of cols c16*8 .. c16*8+7
    int p0 = offsets[node], p1 = offsets[node + 1];
    float4 ed4 = *(const float4*)&ed[(size_t)node * 4];
    float4 sw4 = make_float4(0.f, 0.f, 0.f, 0.f);
    float acc[8];
    #pragma unroll
    for (int i = 0; i < 8; ++i) acc[i] = 0.f;
    for (int base = p0; base < p1; base += 64) {
        int cnt = min(64, p1 - base);
        int myidx = (l < cnt) ? (int)ssrc[base + l] : 0;
        float4 w4 = make_float4(0.f, 0.f, 0.f, 0.f);
        if (l < cnt) {
            float4 e4 = *(const float4*)&es[(size_t)myidx * 4];
            float tv;
            tv = e4.x + ed4.x; tv = tv > 0.f ? tv : LEAKY * tv; w4.x = __expf(tv);
            tv = e4.y + ed4.y; tv = tv > 0.f ? tv : LEAKY * tv; w4.y = __expf(tv);
            tv = e4.z + ed4.z; tv = tv > 0.f ? tv : LEAKY * tv; w4.z = __expf(tv);
            tv = e4.w + ed4.w; tv = tv > 0.f ? tv : LEAKY * tv; w4.w = __expf(tv);
        }
        *(float4*)&wlds[wv][l][0] = w4;
        sw4.x += w4.x; sw4.y += w4.y; sw4.z += w4.z; sw4.w += w4.w;
        __builtin_amdgcn_wave_barrier();
        for (int j = 0; j < cnt; j += 8) {
            int e0 = j + g, e1 = j + 4 + g;
            int c0v = min(e0, cnt - 1), c1v = min(e1, cnt - 1);
            int s0 = __shfl(myidx, c0v);
            int s1 = __shfl(myidx, c1v);
            float x0 = (e0 < cnt) ? wlds[wv][c0v][h] : 0.f;
            float x1 = (e1 < cnt) ? wlds[wv][c1v][h] : 0.f;
            uint4 r0 = *(const uint4*)&h1b[(size_t)s0 * 128 + c16 * 8];
            uint4 r1 = *(const uint4*)&h1b[(size_t)s1 * 128 + c16 * 8];
            acc[0] = fmaf(x0, bf2f_lo(r0.x), acc[0]);
            acc[1] = fmaf(x0, bf2f_hi(r0.x), acc[1]);
            acc[2] = fmaf(x0, bf2f_lo(r0.y), acc[2]);
            acc[3] = fmaf(x0, bf2f_hi(r0.y), acc[3]);
            acc[4] = fmaf(x0, bf2f_lo(r0.z), acc[4]);
            acc[5] = fmaf(x0, bf2f_hi(r0.z), acc[5]);
            acc[6] = fmaf(x0, bf2f_lo(r0.w), acc[6]);
            acc[7] = fmaf(x0, bf2f_hi(r0.w), acc[7]);
            acc[0] = fmaf(x1, bf2f_lo(r1.x), acc[0]);
            acc[1] = fmaf(x1, bf2f_hi(r1.x), acc[1]);
            acc[2] = fmaf(x1, bf2f_lo(r1.y), acc[2]);
            acc[3] = fmaf(x1, bf2f_hi(r1.y), acc[3]);
            acc[4] = fmaf(x1, bf2f_lo(r1.z), acc[4]);
            acc[5] = fmaf(x1, bf2f_hi(r1.z), acc[5]);
            acc[6] = fmaf(x1, bf2f_lo(r1.w), acc[6]);
            acc[7] = fmaf(x1, bf2f_hi(r1.w), acc[7]);
        }
    }
    #pragma unroll
    for (int i = 0; i < 8; ++i) {
        acc[i] += __shfl_xor(acc[i], 16);
        acc[i] += __shfl_xor(acc[i], 32);
    }
    #pragma unroll
    for (int off = 1; off < 64; off <<= 1) {
        sw4.x += __shfl_xor(sw4.x, off);
        sw4.y += __shfl_xor(sw4.y, off);
        sw4.z += __shfl_xor(sw4.z, off);
        sw4.w += __shfl_xor(sw4.w, off);
    }
    if (g == 0) {
        float s = (h == 0) ? sw4.x : (h == 1) ? sw4.y : (h == 2) ? sw4.z : sw4.w;
        float inv = 1.f / s;
        int c0 = c16 * 8;
        float4 b1a = *(const float4*)&b1[c0],    b1b = *(const float4*)&b1[c0 + 4];
        float4 mna = *(const float4*)&mean[c0],  mnb = *(const float4*)&mean[c0 + 4];
        float4 vra = *(const float4*)&var[c0],   vrb = *(const float4*)&var[c0 + 4];
        float4 gma = *(const float4*)&gamma[c0], gmb = *(const float4*)&gamma[c0 + 4];
        float4 bta = *(const float4*)&beta[c0],  btb = *(const float4*)&beta[c0 + 4];
        float bv[8] = {b1a.x, b1a.y, b1a.z, b1a.w, b1b.x, b1b.y, b1b.z, b1b.w};
        float mn[8] = {mna.x, mna.y, mna.z, mna.w, mnb.x, mnb.y, mnb.z, mnb.w};
        float vr[8] = {vra.x, vra.y, vra.z, vra.w, vrb.x, vrb.y, vrb.z, vrb.w};
        float gm[8] = {gma.x, gma.y, gma.z, gma.w, gmb.x, gmb.y, gmb.z, gmb.w};
        float bt[8] = {bta.x, bta.y, bta.z, bta.w, btb.x, btb.y, btb.z, btb.w};
        u16 pk[8];
        #pragma unroll
        for (int i = 0; i < 8; ++i) {
            float o = acc[i] * inv + bv[i];
            o = (o - mn[i]) * rsqrtf(vr[i] + BN_EPS) * gm[i] + bt[i];
            o = o > 0.f ? o : __expf(o) - 1.f;
            pk[i] = f2bf(o);
        }
        *(uint4*)&hbnb[(size_t)node * 128 + c0] = *(uint4*)pk;
    }
}

// layer-2 aggregation: wide uint4 gather over bf16 h2b; es2 folded into
// h2b col 40; 4 loads in flight -> 32 edges/iter; distributed log_softmax
__global__ __launch_bounds__(256) void k_agg2(
        const u16* __restrict__ h2b, const float* __restrict__ ed,
        const int* __restrict__ offsets, const u16* __restrict__ ssrc,
        const float* __restrict__ b2, float* __restrict__ out) {
    __shared__ float wlds[4][64];
    int wv = threadIdx.x >> 6;
    int node = blockIdx.x * 4 + wv;
    if (node >= NN) return;
    int l = threadIdx.x & 63;
    int g = l >> 3;      // edge slot 0..7
    int c8 = l & 7;      // column block: cols c8*8 .. c8*8+7
    int p0 = offsets[node], p1 = offsets[node + 1];
    float edv = ed[node];
    float swacc = 0.f;
    float acc[8];
    #pragma unroll
    for (int i = 0; i < 8; ++i) acc[i] = 0.f;
    for (int base = p0; base < p1; base += 64) {
        int cnt = min(64, p1 - base);
        int myidx = (l < cnt) ? (int)ssrc[base + l] : 0;
        float mw = 0.f;
        if (l < cnt) {
            float esv = bf2f((u32)h2b[(size_t)myidx * 64 + 40]);
            float e = esv + edv;
            e = e > 0.f ? e : LEAKY * e;
            mw = __expf(e);
        }
        wlds[wv][l] = mw;
        swacc += mw;
        __builtin_amdgcn_wave_barrier();
        for (int j = 0; j < cnt; j += 32) {
            int e0 = j + g, e1 = j + 8 + g, e2 = j + 16 + g, e3 = j + 24 + g;
            int c0v = min(e0, cnt - 1), c1v = min(e1, cnt - 1);
            int c2v = min(e2, cnt - 1), c3v = min(e3, cnt - 1);
            int s0 = __shfl(myidx, c0v);
            int s1 = __shfl(myidx, c1v);
            int s2 = __shfl(myidx, c2v);
            int s3 = __shfl(myidx, c3v);
            float x0 = (e0 < cnt) ? wlds[wv][c0v] : 0.f;
            float x1 = (e1 < cnt) ? wlds[wv][c1v] : 0.f;
            float x2 = (e2 < cnt) ? wlds[wv][c2v] : 0.f;
            float x3 = (e3 < cnt) ? wlds[wv][c3v] : 0.f;
            uint4 r0 = *(const uint4*)&h2b[(size_t)s0 * 64 + c8 * 8];
            uint4 r1 = *(const uint4*)&h2b[(size_t)s1 * 64 + c8 * 8];
            uint4 r2 = *(const uint4*)&h2b[(size_t)s2 * 64 + c8 * 8];
            uint4 r3 = *(const uint4*)&h2b[(size_t)s3 * 64 + c8 * 8];
            acc[0] = fmaf(x0, bf2f_lo(r0.x), acc[0]);
            acc[1] = fmaf(x0, bf2f_hi(r0.x), acc[1]);
            acc[2] = fmaf(x0, bf2f_lo(r0.y), acc[2]);
            acc[3] = fmaf(x0, bf2f_hi(r0.y), acc[3]);
            acc[4] = fmaf(x0, bf2f_lo(r0.z), acc[4]);
            acc[5] = fmaf(x0, bf2f_hi(r0.z), acc[5]);
            acc[6] = fmaf(x0, bf2f_lo(r0.w), acc[6]);
            acc[7] = fmaf(x0, bf2f_hi(r0.w), acc[7]);
            acc[0] = fmaf(x1, bf2f_lo(r1.x), acc[0]);
            acc[1] = fmaf(x1, bf2f_hi(r1.x), acc[1]);
            acc[2] = fmaf(x1, bf2f_lo(r1.y), acc[2]);
            acc[3] = fmaf(x1, bf2f_hi(r1.y), acc[3]);
            acc[4] = fmaf(x1, bf2f_lo(r1.z), acc[4]);
            acc[5] = fmaf(x1, bf2f_hi(r1.z), acc[5]);
            acc[6] = fmaf(x1, bf2f_lo(r1.w), acc[6]);
            acc[7] = fmaf(x1, bf2f_hi(r1.w), acc[7]);
            acc[0] = fmaf(x2, bf2f_lo(r2.x), acc[0]);
            acc[1] = fmaf(x2, bf2f_hi(r2.x), acc[1]);
            acc[2] = fmaf(x2, bf2f_lo(r2.y), acc[2]);
            acc[3] = fmaf(x2, bf2f_hi(r2.y), acc[3]);
            acc[4] = fmaf(x2, bf2f_lo(r2.z), acc[4]);
            acc[5] = fmaf(x2, bf2f_hi(r2.z), acc[5]);
            acc[6] = fmaf(x2, bf2f_lo(r2.w), acc[6]);
            acc[7] = fmaf(x2, bf2f_hi(r2.w), acc[7]);
            acc[0] = fmaf(x3, bf2f_lo(r3.x), acc[0]);
            acc[1] = fmaf(x3, bf2f_hi(r3.x), acc[1]);
            acc[2] = fmaf(x3, bf2f_lo(r3.y), acc[2]);
            acc[3] = fmaf(x3, bf2f_hi(r3.y), acc[3]);
            acc[4] = fmaf(x3, bf2f_lo(r3.z), acc[4]);
            acc[5] = fmaf(x3, bf2f_hi(r3.z), acc[5]);
            acc[6] = fmaf(x3, bf2f_lo(r3.w), acc[6]);
            acc[7] = fmaf(x3, bf2f_hi(r3.w), acc[7]);
        }
    }
    #pragma unroll
    for (int i = 0; i < 8; ++i) {
        acc[i] += __shfl_xor(acc[i], 8);
        acc[i] += __shfl_xor(acc[i], 16);
        acc[i] += __shfl_xor(acc[i], 32);
    }
    float s = swacc;
    #pragma unroll
    for (int off = 1; off < 64; off <<= 1) s += __shfl_xor(s, off);
    float inv = 1.f / s;
    bool valid = (c8 < 5);
    int c0 = c8 * 8;
    float v[8];
    float m8 = -1e30f;
    if (valid) {
        float4 b2a = *(const float4*)&b2[c0];
        float4 b2b = *(const float4*)&b2[c0 + 4];
        float bv[8] = {b2a.x, b2a.y, b2a.z, b2a.w, b2b.x, b2b.y, b2b.z, b2b.w};
        #pragma unroll
        for (int i = 0; i < 8; ++i) {
            v[i] = acc[i] * inv + bv[i];
            m8 = fmaxf(m8, v[i]);
        }
    }
    m8 = fmaxf(m8, __shfl_xor(m8, 1));
    m8 = fmaxf(m8, __shfl_xor(m8, 2));
    m8 = fmaxf(m8, __shfl_xor(m8, 4));
    float ex = 0.f;
    if (valid) {
        #pragma unroll
        for (int i = 0; i < 8; ++i) ex += __expf(v[i] - m8);
    }
    ex += __shfl_xor(ex, 1);
    ex += __shfl_xor(ex, 2);
    ex += __shfl_xor(ex, 4);
    if (g == 0 && valid) {
        float lg = m8 + __logf(ex);
        float4 o0 = make_float4(v[0] - lg, v[1] - lg, v[2] - lg, v[3] - lg);
        float4 o1 = make_float4(v[4] - lg, v[5] - lg, v[6] - lg, v[7] - lg);
        *(float4*)&out[(size_t)node * 40 + c0] = o0;
        *(float4*)&out[(size_t)node * 40 + c0 + 4] = o1;
    }
}

extern "C" void kernel_launch(void* const* d_in, const int* in_sizes, int n_in,
                              void* d_out, int out_size, void* d_ws, size_t ws_size,
                              hipStream_t stream) {
    const float* x   = (const float*)d_in[0];
    const int*   ei  = (const int*)d_in[1];
    const float* W1  = (const float*)d_in[2];
    const float* a1s = (const float*)d_in[3];
    const float* a1d = (const float*)d_in[4];
    const float* b1  = (const float*)d_in[5];
    const float* bng = (const float*)d_in[6];
    const float* bnb = (const float*)d_in[7];
    const float* bnm = (const float*)d_in[8];
    const float* bnv = (const float*)d_in[9];
    const float* W2  = (const float*)d_in[10];
    const float* a2s = (const float*)d_in[11];
    const float* a2d = (const float*)d_in[12];
    const float* b2  = (const float*)d_in[13];
    float* out = (float*)d_out;

    char* ws = (char*)d_ws;
    size_t off = 0;
    auto alloc = [&](size_t bytes) -> void* {
        void* p = ws + off;
        off = (off + bytes + 255) & ~(size_t)255;
        return p;
    };
    int*   cntb     = (int*)alloc((size_t)NB * NBB * 4);
    int*   excl     = (int*)alloc((size_t)NB * NBB * 4);
    int*   offsets  = (int*)alloc((size_t)(NN + 1) * 4);
    u32*   packed   = (u32*)alloc((size_t)ETOT * 4);
    u16*   ssrc     = (u16*)alloc((size_t)ETOT * 2);
    u16*   Wt1      = (u16*)alloc((size_t)BN1 * 128 * 2);
    u16*   Wt2      = (u16*)alloc((size_t)BN2 * 128 * 2);
    u16*   h1b      = (u16*)alloc((size_t)NN * 128 * 2);
    float* es1      = (float*)alloc((size_t)NN * 4 * 4);
    float* ed1      = (float*)alloc((size_t)NN * 4 * 4);
    u16*   hbnb     = (u16*)alloc((size_t)NN * 128 * 2);
    u16*   h2b      = (u16*)alloc((size_t)NN * 64 * 2);
    float* ed2      = (float*)alloc((size_t)NN * 4);

    k_binA_prep<<<NBB + PREPB, 256, 0, stream>>>(ei, cntb, W1, a1s, a1d,
                                                 W2, a2s, a2d, Wt1, Wt2);
    k_scanONE<<<1, 1024, 0, stream>>>(cntb, excl);
    k_binB<<<NBB, 256, 0, stream>>>(ei, excl, packed);
    k_binC<<<NB, 256, 0, stream>>>(packed, excl, offsets, ssrc);
    k_mm1<<<(NN + 127) / 128, 256, 0, stream>>>(x, Wt1, h1b, es1, ed1);
    k_agg1<<<(NN + 3) / 4, 256, 0, stream>>>(h1b, es1, ed1, offsets, ssrc,
                                             b1, bng, bnb, bnm, bnv, hbnb);
    k_mm2<<<(NN + 127) / 128, 256, 0, stream>>>(hbnb, Wt2, h2b, ed2);
    k_agg2<<<(NN + 3) / 4, 256, 0, stream>>>(h2b, ed2, offsets, ssrc, b2, out);
}